// Round 10
// baseline (1901.425 us; speedup 1.0000x reference)
//
#include <hip/hip_runtime.h>
#include <hip/hip_bf16.h>
#include <stdint.h>

#define NG 64

typedef __attribute__((ext_vector_type(8))) short bf16x8;
typedef __attribute__((ext_vector_type(4))) float f32x4;

#define AS1 __attribute__((address_space(1)))
#define AS3 __attribute__((address_space(3)))

static __device__ __forceinline__ unsigned short f2b(float f) {
    unsigned u = __float_as_uint(f);
    return (unsigned short)((u + 0x7fffu + ((u >> 16) & 1u)) >> 16);
}
static __device__ __forceinline__ float b2f(unsigned short h) {
    return __uint_as_float(((unsigned)h) << 16);
}
static __device__ __forceinline__ void gl16(const void* g, void* l) {
    __builtin_amdgcn_global_load_lds(
        (const AS1 void*)(uintptr_t)g,
        (AS3 void*)(unsigned)(uintptr_t)l, 16, 0, 0);
}
// bijective XCD-chunk swizzle (m204)
static __device__ __forceinline__ int xcd_swz(int bid, int nwg) {
    int q = nwg >> 3, r = nwg & 7;
    int xcd = bid & 7, oidx = bid >> 3;
    return (xcd < r ? xcd * (q + 1) : r * (q + 1) + (xcd - r) * q) + oidx;
}

// ---------------- graph build ----------------
__global__ void initcnt_k(int* cnt, int n) {
    int i = blockIdx.x * blockDim.x + threadIdx.x;
    if (i < n) cnt[i] = 0;
}
__global__ void count_k(const int* __restrict__ dst, int* cnt, int E) {
    int e = blockIdx.x * blockDim.x + threadIdx.x;
    if (e < E) atomicAdd(&cnt[dst[e]], 1);
}
__global__ void scan1_k(const int* __restrict__ cnt, int* __restrict__ scan,
                        int* __restrict__ bsum, int n) {
    __shared__ int wsum[16];
    int tid = threadIdx.x, lane = tid & 63, wid = tid >> 6;
    int i = blockIdx.x * 1024 + tid;
    int x = (i < n) ? cnt[i] : 0;
#pragma unroll
    for (int off = 1; off < 64; off <<= 1) {
        int t = __shfl_up(x, off);
        if (lane >= off) x += t;
    }
    if (lane == 63) wsum[wid] = x;
    __syncthreads();
    if (tid < 16) {
        int s = wsum[tid];
#pragma unroll
        for (int off = 1; off < 16; off <<= 1) {
            int t = __shfl_up(s, off);
            if (tid >= off) s += t;
        }
        wsum[tid] = s;
    }
    __syncthreads();
    int add = wid ? wsum[wid - 1] : 0;
    if (i < n) scan[i] = x + add;
    if (tid == 1023) bsum[blockIdx.x] = x + add;
}
__global__ void scan2_k(int* bsum, int nb) {
    int tid = threadIdx.x;
    int x = (tid < nb) ? bsum[tid] : 0;
#pragma unroll
    for (int off = 1; off < 64; off <<= 1) {
        int t = __shfl_up(x, off);
        if (tid >= off) x += t;
    }
    if (tid < nb) bsum[tid] = x;
}
__global__ void scan3f_k(const int* __restrict__ scan, const int* __restrict__ bsum,
                         const int* __restrict__ cnt,
                         int* __restrict__ rowptr, int* __restrict__ fill,
                         float* __restrict__ dinv, int n) {
    int i = blockIdx.x * blockDim.x + threadIdx.x;
    if (i >= n) return;
    int b = i >> 10;
    int rp1 = scan[i] + (b ? bsum[b - 1] : 0);
    rowptr[i + 1] = rp1;
    int rp0 = rp1 - cnt[i];
    if (i == 0) rowptr[0] = 0;
    fill[i] = rp0;
    dinv[i] = rsqrtf((float)(cnt[i] + 1));
}
__global__ void fill_k(const int* __restrict__ src, const int* __restrict__ dst,
                       int* fill, int* csr, int E) {
    int e = blockIdx.x * blockDim.x + threadIdx.x;
    if (e < E) {
        int d = dst[e];
        int pos = atomicAdd(&fill[d], 1);
        csr[pos] = src[e];
    }
}

// W [K][Nout] fp32 -> Wt rows [0,Nrows) x [0,Kpad) bf16 (transposed, zero-padded)
// remap=1: feat layout [f1(128)|f3(320)|f2(21)|pad]
__global__ void wtconv_k(const float* __restrict__ W, int K, int Nout,
                         unsigned short* __restrict__ Wt, int Kpad, int Nrows, int remap) {
    __shared__ float t[32][33];
    int k0 = blockIdx.x * 32, n0 = blockIdx.y * 32;
    int cx = threadIdx.x & 31, ry = threadIdx.x >> 5;
#pragma unroll
    for (int p = 0; p < 4; ++p) {
        int k = k0 + ry + p * 8, nn = n0 + cx;
        int ko = k;
        bool kvalid;
        if (remap) {
            ko = (k < 448) ? k + 21 : k - 448;
            kvalid = (k < 469);
        } else {
            kvalid = (k < K);
        }
        t[ry + p * 8][cx] = (kvalid && nn < Nout) ? W[(size_t)ko * Nout + nn] : 0.0f;
    }
    __syncthreads();
#pragma unroll
    for (int p = 0; p < 4; ++p) {
        int nn = n0 + ry + p * 8, k = k0 + cx;
        if (nn < Nrows) Wt[(size_t)nn * Kpad + k] = f2b(t[cx][ry + p * 8]);
    }
}

__global__ void biascat_k(const float* __restrict__ b0, const float* __restrict__ b1,
                          float* __restrict__ out) {
    int i = threadIdx.x + blockIdx.x * blockDim.x;
    if (i >= 960) return;
    int seg = i >= 480, c = i - seg * 480;
    const float* b = seg ? b1 : b0;
    out[i] = (c < 469) ? b[c] : 0.0f;
}

// ---------------- tiny fl2 (21x21) -> feat cols [448,480) ----------------
__global__ void fl2_k(const float* __restrict__ x, int ldx,
                      const float* __restrict__ W, const float* __restrict__ b,
                      unsigned short* __restrict__ out, int ldo, int n) {
    __shared__ float Ws[441];
    __shared__ float Bs[21];
    int tid = threadIdx.x;
    for (int i = tid; i < 441; i += 256) Ws[i] = W[i];
    if (tid < 21) Bs[tid] = b[tid];
    __syncthreads();
    int row = blockIdx.x * 256 + tid;
    if (row >= n) return;
    float xv[21];
#pragma unroll
    for (int j = 0; j < 21; ++j) xv[j] = x[(size_t)row * ldx + j];
    for (int c = 0; c < 32; ++c) {
        float v = 0.0f;
        if (c < 21) {
            float a = Bs[c];
#pragma unroll
            for (int j = 0; j < 21; ++j) a = fmaf(xv[j], Ws[j * 21 + c], a);
            v = fmaxf(a, 0.0f);
        }
        out[(size_t)row * ldo + 448 + c] = f2b(v);
    }
}

// ---------------- bf16 MFMA GEMM template: C = relu(A@W+b) ----------------
// K-loop unrolled 2x: two BK=32 tiles staged side-by-side in LDS before ONE
// barrier pair (halves the vmcnt(0)+barrier drain count; row stride stays
// 64B = free 2-way bank aliasing). 32-wide tail for K%64.
template<int NI, bool A32>
__global__ __launch_bounds__(256) void mgemm_t(
    const void* __restrict__ Aptr, int lda, int Mreal,
    const unsigned short* __restrict__ Bt, int ldb,
    const float* __restrict__ bias,
    unsigned short* __restrict__ C, int ldc, int coff,
    int K, int Nout, int Nzero, int GX) {
    constexpr int BNT = NI * 32;
    __shared__ unsigned short As[2 * 128 * 32];
    __shared__ unsigned short Bs[2 * BNT * 32];
    const int tid = threadIdx.x;
    const int w = tid >> 6, lane = tid & 63;

    const int swz = xcd_swz(blockIdx.x, gridDim.x);
    const int m0 = (swz / GX) * 128, n0 = (swz % GX) * BNT;

    const int wr = w >> 1, wc = w & 1;

    f32x4 acc[4][NI];
#pragma unroll
    for (int i = 0; i < 4; ++i)
#pragma unroll
        for (int j = 0; j < NI; ++j) acc[i][j] = (f32x4){0.f, 0.f, 0.f, 0.f};

    const int ko = (lane >> 4) * 8;
    const int rA = wr * 64 + (lane & 15);
    const int rB = wc * (NI * 16) + (lane & 15);

    auto stage = [&](int kk, int h) {
        if constexpr (A32) {
            const float* Af = (const float*)Aptr;
#pragma unroll
            for (int j = 0; j < 2; ++j) {
                int c = w * 2 + j;
                int id2 = c * 64 + lane;
                int row = id2 >> 2, cc = id2 & 3;
                int gm = m0 + row; if (gm > Mreal - 1) gm = Mreal - 1;
                const float* ap = Af + (size_t)gm * lda + kk + cc * 8;
                float4 v0 = *(const float4*)ap;
                float4 v1 = *(const float4*)(ap + 4);
                unsigned short t[8] = {f2b(v0.x), f2b(v0.y), f2b(v0.z), f2b(v0.w),
                                       f2b(v1.x), f2b(v1.y), f2b(v1.z), f2b(v1.w)};
                *(bf16x8*)&As[h * 4096 + row * 32 + cc * 8] = *(const bf16x8*)t;
            }
        } else {
            const unsigned short* Ab = (const unsigned short*)Aptr;
#pragma unroll
            for (int j = 0; j < 2; ++j) {
                int c = w * 2 + j;
                gl16(Ab + (size_t)(m0 + (((c * 64 + lane) >> 2))) * lda + kk + ((c * 64 + lane) & 3) * 8,
                     &As[h * 4096 + c * 512]);
            }
        }
#pragma unroll
        for (int j = 0; j < NI / 2; ++j) {
            int c = w * (NI / 2) + j;
            gl16(Bt + (size_t)(n0 + (((c * 64 + lane) >> 2))) * ldb + kk + ((c * 64 + lane) & 3) * 8,
                 &Bs[h * (BNT * 32) + c * 512]);
        }
    };
    auto compute = [&](int h) {
        bf16x8 a[4], b[NI];
#pragma unroll
        for (int i = 0; i < 4; ++i)
            a[i] = *(const bf16x8*)&As[h * 4096 + (rA + i * 16) * 32 + ko];
#pragma unroll
        for (int j = 0; j < NI; ++j)
            b[j] = *(const bf16x8*)&Bs[h * (BNT * 32) + (rB + j * 16) * 32 + ko];
#pragma unroll
        for (int i = 0; i < 4; ++i)
#pragma unroll
            for (int j = 0; j < NI; ++j)
                acc[i][j] = __builtin_amdgcn_mfma_f32_16x16x32_bf16(a[i], b[j], acc[i][j], 0, 0, 0);
    };

    int k0 = 0;
    for (; k0 + 64 <= K; k0 += 64) {
        stage(k0, 0);
        stage(k0 + 32, 1);
        __syncthreads();
        compute(0);
        compute(1);
        __syncthreads();
    }
    if (k0 < K) {
        stage(k0, 0);
        __syncthreads();
        compute(0);
        __syncthreads();
    }

    const int cn = lane & 15, r4 = (lane >> 4) * 4;
    for (int ni = 0; ni < NI; ++ni) {
        int col = n0 + wc * (NI * 16) + ni * 16 + cn;
        if (col >= Nzero) continue;
        bool real = col < Nout;
        float bb = real ? bias[col] : 0.0f;
#pragma unroll
        for (int mi = 0; mi < 4; ++mi) {
#pragma unroll
            for (int rr = 0; rr < 4; ++rr) {
                int row = m0 + wr * 64 + mi * 16 + r4 + rr;
                float x = real ? fmaxf(acc[mi][ni][rr] + bb, 0.0f) : 0.0f;
                C[(size_t)row * ldc + coff + col] = f2b(x);
            }
        }
    }
}

// ---------------- fl1 split-K (ksplit=3, K-chunk 2048, 2x-unrolled K-loop) ----------------
__global__ __launch_bounds__(256) void fl1part_k(
    const float* __restrict__ A, int lda, int Mreal,
    const unsigned short* __restrict__ Bt, int ldb,
    float* __restrict__ part, int MT, int Mpad) {
    __shared__ unsigned short As[2 * 128 * 32];
    __shared__ unsigned short Bs[2 * 128 * 32];
    const int tid = threadIdx.x;
    const int w = tid >> 6, lane = tid & 63;
    const int mt = blockIdx.x % MT, ks = blockIdx.x / MT;
    const int m0 = mt * 128;
    const int kbeg = ks * 2048, kend = kbeg + 2048;
    const int wr = w >> 1, wc = w & 1;

    f32x4 acc[4][4];
#pragma unroll
    for (int i = 0; i < 4; ++i)
#pragma unroll
        for (int j = 0; j < 4; ++j) acc[i][j] = (f32x4){0.f, 0.f, 0.f, 0.f};

    const int ko = (lane >> 4) * 8;
    const int rA = wr * 64 + (lane & 15);
    const int rB = wc * 64 + (lane & 15);

    auto stage = [&](int kk, int h) {
#pragma unroll
        for (int j = 0; j < 2; ++j) {
            int c = w * 2 + j;
            int id2 = c * 64 + lane;
            int row = id2 >> 2, cc = id2 & 3;
            int gm = m0 + row; if (gm > Mreal - 1) gm = Mreal - 1;
            const float* ap = A + (size_t)gm * lda + kk + cc * 8;
            float4 v0 = *(const float4*)ap;
            float4 v1 = *(const float4*)(ap + 4);
            unsigned short t[8] = {f2b(v0.x), f2b(v0.y), f2b(v0.z), f2b(v0.w),
                                   f2b(v1.x), f2b(v1.y), f2b(v1.z), f2b(v1.w)};
            *(bf16x8*)&As[h * 4096 + row * 32 + cc * 8] = *(const bf16x8*)t;
            gl16(Bt + (size_t)row * ldb + kk + cc * 8, &Bs[h * 4096 + c * 512]);
        }
    };
    auto compute = [&](int h) {
        bf16x8 a[4], b[4];
#pragma unroll
        for (int i = 0; i < 4; ++i)
            a[i] = *(const bf16x8*)&As[h * 4096 + (rA + i * 16) * 32 + ko];
#pragma unroll
        for (int j = 0; j < 4; ++j)
            b[j] = *(const bf16x8*)&Bs[h * 4096 + (rB + j * 16) * 32 + ko];
#pragma unroll
        for (int i = 0; i < 4; ++i)
#pragma unroll
            for (int j = 0; j < 4; ++j)
                acc[i][j] = __builtin_amdgcn_mfma_f32_16x16x32_bf16(a[i], b[j], acc[i][j], 0, 0, 0);
    };

    for (int k0 = kbeg; k0 < kend; k0 += 64) {
        stage(k0, 0);
        stage(k0 + 32, 1);
        __syncthreads();
        compute(0);
        compute(1);
        __syncthreads();
    }

    float* pb = part + (size_t)ks * Mpad * 128;
    const int cn = lane & 15, r4 = (lane >> 4) * 4;
#pragma unroll
    for (int ni = 0; ni < 4; ++ni) {
        int col = wc * 64 + ni * 16 + cn;
#pragma unroll
        for (int mi = 0; mi < 4; ++mi) {
#pragma unroll
            for (int rr = 0; rr < 4; ++rr) {
                int row = m0 + wr * 64 + mi * 16 + r4 + rr;
                pb[(size_t)row * 128 + col] = acc[mi][ni][rr];
            }
        }
    }
}

__global__ void fl1red_k(const float* __restrict__ part, const float* __restrict__ bias,
                         unsigned short* __restrict__ feat, int Mpad) {
    int i = blockIdx.x * blockDim.x + threadIdx.x;
    if (i >= Mpad * 32) return;
    int row = i >> 5, c = (i & 31) * 4;
    size_t base = (size_t)row * 128 + c;
    size_t stride = (size_t)Mpad * 128;
    float4 p0 = *(const float4*)(part + base);
    float4 p1 = *(const float4*)(part + stride + base);
    float4 p2 = *(const float4*)(part + 2 * stride + base);
    float4 bb = *(const float4*)(bias + c);
    ushort4 o;
    o.x = f2b(fmaxf(p0.x + p1.x + p2.x + bb.x, 0.0f));
    o.y = f2b(fmaxf(p0.y + p1.y + p2.y + bb.y, 0.0f));
    o.z = f2b(fmaxf(p0.z + p1.z + p2.z + bb.z, 0.0f));
    o.w = f2b(fmaxf(p0.w + p1.w + p2.w + bb.w, 0.0f));
    *(ushort4*)(feat + (size_t)row * 480 + c) = o;
}

// ---------------- GCN aggregation (XCD-chunked node assignment) ----------------
__global__ __launch_bounds__(256) void agg_wave_k(
    const unsigned short* __restrict__ in, unsigned short* __restrict__ out,
    const float* __restrict__ dinv, const int* __restrict__ rowptr,
    const int* __restrict__ csr, int D8, int ld, int n) {
    int lane = threadIdx.x & 63;
    int node = xcd_swz(blockIdx.x, gridDim.x) * 4 + (threadIdx.x >> 6);
    if (node >= n) return;
    bool act = lane < D8;
    float di = dinv[node];
    float acc[8];
#pragma unroll
    for (int t = 0; t < 8; ++t) acc[t] = 0.0f;
    if (act) {
        bf16x8 v = *(const bf16x8*)(in + (size_t)node * ld + lane * 8);
#pragma unroll
        for (int t = 0; t < 8; ++t) acc[t] = di * b2f((unsigned short)v[t]);
    }
    int s = rowptr[node], e = rowptr[node + 1];
    for (int c = s; c < e; c += 64) {
        int m = e - c; if (m > 64) m = 64;
        int idx = (c + lane < e) ? csr[c + lane] : 0;
        float wl = dinv[idx];
        for (int j = 0; j < m; ++j) {
            int src = __shfl(idx, j);
            float wgt = __shfl(wl, j);
            if (act) {
                bf16x8 v = *(const bf16x8*)(in + (size_t)src * ld + lane * 8);
#pragma unroll
                for (int t = 0; t < 8; ++t) acc[t] = fmaf(wgt, b2f((unsigned short)v[t]), acc[t]);
            }
        }
    }
    if (act) {
        unsigned short o[8];
#pragma unroll
        for (int t = 0; t < 8; ++t) o[t] = f2b(di * acc[t]);
        *(bf16x8*)(out + (size_t)node * ld + lane * 8) = *(const bf16x8*)o;
    }
}

__global__ void agg_block_k(
    const unsigned short* __restrict__ in, unsigned short* __restrict__ out,
    const float* __restrict__ dinv, const int* __restrict__ rowptr,
    const int* __restrict__ csr, int D8, int ld, int n) {
    int i = xcd_swz(blockIdx.x, gridDim.x);
    int tid = threadIdx.x;
    __shared__ int s_src[64];
    __shared__ float s_w[64];
    bool act = tid < D8;
    float di = dinv[i];
    float acc[8];
#pragma unroll
    for (int t = 0; t < 8; ++t) acc[t] = 0.0f;
    if (act) {
        bf16x8 v = *(const bf16x8*)(in + (size_t)i * ld + tid * 8);
#pragma unroll
        for (int t = 0; t < 8; ++t) acc[t] = di * b2f((unsigned short)v[t]);
    }
    int s = rowptr[i], e = rowptr[i + 1];
    for (int c = s; c < e; c += 64) {
        int k = c + tid;
        if (tid < 64 && k < e) { int sn = csr[k]; s_src[tid] = sn; s_w[tid] = dinv[sn]; }
        __syncthreads();
        int m = e - c; if (m > 64) m = 64;
        for (int j = 0; j < m; ++j) {
            int sn = s_src[j];
            float wgt = s_w[j];
            if (act) {
                bf16x8 v = *(const bf16x8*)(in + (size_t)sn * ld + tid * 8);
#pragma unroll
                for (int t = 0; t < 8; ++t) acc[t] = fmaf(wgt, b2f((unsigned short)v[t]), acc[t]);
            }
        }
        __syncthreads();
    }
    if (act) {
        unsigned short o[8];
#pragma unroll
        for (int t = 0; t < 8; ++t) o[t] = f2b(di * acc[t]);
        *(bf16x8*)(out + (size_t)i * ld + tid * 8) = *(const bf16x8*)o;
    }
}

// ---------------- mean pool (vectorized bf16x8) ----------------
__global__ void pool_k(const unsigned short* __restrict__ in, int ld,
                       const int* __restrict__ batch,
                       float* __restrict__ out, int n, int D) {
    int g = blockIdx.y;
    int d8 = blockIdx.x * blockDim.x + threadIdx.x;
    if (d8 * 8 >= ld) return;
    int lo = 0, hi = n;
    while (lo < hi) { int mid = (lo + hi) >> 1; if (batch[mid] < g) lo = mid + 1; else hi = mid; }
    int start = lo;
    lo = start; hi = n;
    while (lo < hi) { int mid = (lo + hi) >> 1; if (batch[mid] < g + 1) lo = mid + 1; else hi = mid; }
    int end = lo;
    float s[8];
#pragma unroll
    for (int j = 0; j < 8; ++j) s[j] = 0.0f;
#pragma unroll 4
    for (int r = start; r < end; r++) {
        bf16x8 v = *(const bf16x8*)(in + (size_t)r * ld + d8 * 8);
#pragma unroll
        for (int j = 0; j < 8; ++j) s[j] += b2f((unsigned short)v[j]);
    }
    float inv = 1.0f / fmaxf((float)(end - start), 1.0f);
#pragma unroll
    for (int j = 0; j < 8; ++j) {
        int d = d8 * 8 + j;
        if (d < D) out[(size_t)g * D + d] = s[j] * inv;
    }
}

// ---------------- skinny head GEMM ----------------
__global__ __launch_bounds__(256) void sgemm_part_k(
    const float* __restrict__ A, int lda,
    const float* __restrict__ W, int ldw,
    float* __restrict__ part, int K, int Nout, int ksplit) {
    const int n0 = blockIdx.x * 64;
    const int ks = blockIdx.y;
    const int kbeg = (int)(((long long)K * ks) / ksplit);
    const int kend = (int)(((long long)K * (ks + 1)) / ksplit);
    const int tx = threadIdx.x & 63, ty = threadIdx.x >> 6;
    __shared__ float As[64][65];
    float acc[16];
#pragma unroll
    for (int r = 0; r < 16; ++r) acc[r] = 0.0f;

    for (int kb = kbeg; kb < kend; kb += 64) {
        int kc = kend - kb; if (kc > 64) kc = 64;
        for (int i = threadIdx.x; i < 64 * 64; i += 256) {
            int r = i >> 6, c = i & 63;
            As[r][c] = (c < kc) ? A[(size_t)r * lda + kb + c] : 0.0f;
        }
        __syncthreads();
        if (n0 + tx < Nout) {
            for (int k = 0; k < kc; ++k) {
                float w = W[(size_t)(kb + k) * ldw + n0 + tx];
#pragma unroll
                for (int r = 0; r < 16; ++r)
                    acc[r] = fmaf(As[ty * 16 + r][k], w, acc[r]);
            }
        }
        __syncthreads();
    }
    if (n0 + tx < Nout) {
#pragma unroll
        for (int r = 0; r < 16; ++r)
            part[((size_t)ks * 64 + ty * 16 + r) * Nout + n0 + tx] = acc[r];
    }
}

__global__ void sgemm_reduce_k(const float* __restrict__ part, const float* __restrict__ bias,
                               float* __restrict__ C, int ldc, int Nout, int ksplit, int act) {
    int i = blockIdx.x * blockDim.x + threadIdx.x;
    if (i >= NG * Nout) return;
    int m = i / Nout, n = i - m * Nout;
    float v = bias[n];
    for (int s = 0; s < ksplit; ++s) v += part[((size_t)s * 64 + m) * Nout + n];
    if (act == 2) v = 1.0f / (1.0f + expf(-v));
    C[(size_t)m * ldc + n] = v;
}

// ---------------- fused batchnorm ----------------
__global__ void bn_k(const float* __restrict__ z, const float* __restrict__ g,
                     const float* __restrict__ b, float* __restrict__ out) {
    int c = blockIdx.x * blockDim.x + threadIdx.x;
    if (c >= 1024) return;
    float s = 0.0f, s2 = 0.0f;
    for (int r = 0; r < NG; r++) { float v = z[r * 1024 + c]; s += v; s2 += v * v; }
    float mu = s / (float)NG;
    float var = s2 / (float)NG - mu * mu;
    float sc = g[c] * rsqrtf(var + 1e-5f);
    float sh = b[c] - mu * sc;
    for (int r = 0; r < NG; r++)
        out[r * 1024 + c] = fmaxf(fmaf(z[r * 1024 + c], sc, sh), 0.0f);
}

// ---------------- launch ----------------
extern "C" void kernel_launch(void* const* d_in, const int* in_sizes, int n_in,
                              void* d_out, int out_size, void* d_ws, size_t ws_size,
                              hipStream_t stream) {
    (void)n_in; (void)out_size; (void)ws_size;
    const float* prot_x = (const float*)d_in[0];
    const int*   eidx   = (const int*)d_in[1];
    const int*   batch  = (const int*)d_in[2];
    const float* fl1_W = (const float*)d_in[3],  *fl1_b = (const float*)d_in[4];
    const float* fl2_W = (const float*)d_in[5],  *fl2_b = (const float*)d_in[6];
    const float* fl3_W = (const float*)d_in[7],  *fl3_b = (const float*)d_in[8];
    const float* pdb1_W = (const float*)d_in[9],  *pdb1_b = (const float*)d_in[10];
    const float* pdb2_W = (const float*)d_in[11], *pdb2_b = (const float*)d_in[12];
    const float* af1_W  = (const float*)d_in[13], *af1_b  = (const float*)d_in[14];
    const float* af2_W  = (const float*)d_in[15], *af2_b  = (const float*)d_in[16];
    const float* pdb3_W = (const float*)d_in[17], *pdb3_b = (const float*)d_in[18];
    const float* fc1_W  = (const float*)d_in[19], *fc1_b  = (const float*)d_in[20];
    const float* bn_g   = (const float*)d_in[21], *bn_b   = (const float*)d_in[22];
    const float* fc2_W  = (const float*)d_in[23], *fc2_b  = (const float*)d_in[24];

    const int N = in_sizes[2];
    const int E = in_sizes[1] / 2;
    const int* e_src = eidx;
    const int* e_dst = eidx + E;
    const int Mpad = ((N + 127) / 128) * 128;
    const int MT = Mpad / 128;
    const int NB = (N + 1023) / 1024;

    // ---------- workspace ----------
    char* wp = (char*)d_ws;
    auto alloc = [&](size_t bytes) -> char* {
        char* r = wp; wp += (bytes + 255) & ~(size_t)255; return r;
    };
    unsigned short* feat = (unsigned short*)alloc((size_t)Mpad * 480 * 2);
    unsigned short* tmp1 = (unsigned short*)alloc((size_t)Mpad * 480 * 2);
    unsigned short* hxy  = (unsigned short*)alloc((size_t)Mpad * 960 * 2);
    unsigned short* tmp2 = (unsigned short*)alloc((size_t)Mpad * 960 * 2);
    unsigned short* zb   = (unsigned short*)alloc((size_t)Mpad * 1920 * 2);
    unsigned short* zagg = (unsigned short*)alloc((size_t)Mpad * 1920 * 2);
    unsigned short* zout = (unsigned short*)alloc((size_t)Mpad * 1888 * 2);
    unsigned short* wt_fl1  = (unsigned short*)alloc((size_t)128 * 6144 * 2);
    unsigned short* wt_fl3  = (unsigned short*)alloc((size_t)384 * 320 * 2);
    unsigned short* wt_c1   = (unsigned short*)alloc((size_t)1024 * 480 * 2);
    unsigned short* wt_pdb2 = (unsigned short*)alloc((size_t)1024 * 480 * 2);
    unsigned short* wt_af2  = (unsigned short*)alloc((size_t)1152 * 480 * 2);
    unsigned short* wt_pdb3 = (unsigned short*)alloc((size_t)1920 * 1920 * 2);
    float* f_bias1 = (float*)alloc(960 * 4);
    float* f_dinv = (float*)alloc((size_t)N * 4);
    float* f_pool = (float*)alloc((size_t)NG * 1876 * 4);
    float* f_fc1  = (float*)alloc((size_t)NG * 1024 * 4);
    float* f_bn   = (float*)alloc((size_t)NG * 1024 * 4);
    float* f_part = (float*)alloc((size_t)16 * 64 * 1024 * 4);
    float* f_flp  = (float*)alloc((size_t)3 * Mpad * 128 * 4);
    int* i_cnt    = (int*)alloc((size_t)N * 4);
    int* i_scan   = (int*)alloc((size_t)N * 4);
    int* i_bsum   = (int*)alloc(64 * 4);
    int* i_rowptr = (int*)alloc((size_t)(N + 1) * 4);
    int* i_fill   = (int*)alloc((size_t)N * 4);
    int* i_csr    = (int*)alloc((size_t)E * 4);

    // NI=6 (BN=192) bf16-A GEMM
    auto mg = [&](const unsigned short* A, int lda, const unsigned short* Wt, int ldb,
                  const float* bias, unsigned short* C, int ldc, int coff,
                  int K, int Nout, int Nzero) {
        int gx = (Nzero + 191) / 192;
        mgemm_t<6, false><<<gx * MT, 256, 0, stream>>>(
            A, lda, Mpad, Wt, ldb, bias, C, ldc, coff, K, Nout, Nzero, gx);
    };
    // NI=4 (BN=128) fp32-A GEMM
    auto mgf = [&](const float* A, int lda, const unsigned short* Wt, int ldb,
                   const float* bias, unsigned short* C, int ldc, int coff,
                   int K, int Nout, int Nzero) {
        int gx = (Nzero + 127) / 128;
        mgemm_t<4, true><<<gx * MT, 256, 0, stream>>>(
            A, lda, N, Wt, ldb, bias, C, ldc, coff, K, Nout, Nzero, gx);
    };
    auto wt = [&](const float* W, int K, int Nout, unsigned short* Wt, int Kpad, int Nrows, int remap) {
        wtconv_k<<<dim3(Kpad / 32, Nrows / 32), 256, 0, stream>>>(W, K, Nout, Wt, Kpad, Nrows, remap);
    };

    // graph build
    initcnt_k<<<(N + 255) / 256, 256, 0, stream>>>(i_cnt, N);
    count_k<<<(E + 255) / 256, 256, 0, stream>>>(e_dst, i_cnt, E);
    scan1_k<<<NB, 1024, 0, stream>>>(i_cnt, i_scan, i_bsum, N);
    scan2_k<<<1, 64, 0, stream>>>(i_bsum, NB);
    scan3f_k<<<(N + 255) / 256, 256, 0, stream>>>(i_scan, i_bsum, i_cnt, i_rowptr, i_fill, f_dinv, N);
    fill_k<<<(E + 255) / 256, 256, 0, stream>>>(e_src, e_dst, i_fill, i_csr, E);

    // weight prep (feat layout: [f1(128) | f3(320) | f2(21) | pad(11)])
    wt(fl1_W, 6144, 128, wt_fl1, 6144, 128, 0);
    wt(fl3_W, 320, 320, wt_fl3, 320, 384, 0);
    wt(pdb1_W, 469, 469, wt_c1, 480, 480, 1);
    wt(af1_W, 469, 469, wt_c1 + (size_t)480 * 480, 480, 544, 1);
    wt(pdb2_W, 469, 938, wt_pdb2, 480, 1024, 0);
    wt(af2_W, 469, 938, wt_af2, 480, 1152, 0);
    wt(pdb3_W, 1876, 1876, wt_pdb3, 1920, 1920, 0);
    biascat_k<<<4, 256, 0, stream>>>(pdb1_b, af1_b, f_bias1);

    // feature linears
    fl2_k<<<(N + 255) / 256, 256, 0, stream>>>(prot_x, 6485, fl2_W, fl2_b, feat, 480, N);
    fl1part_k<<<MT * 3, 256, 0, stream>>>(prot_x + 21, 6485, N, wt_fl1, 6144, f_flp, MT, Mpad);
    fl1red_k<<<(Mpad * 32 + 255) / 256, 256, 0, stream>>>(f_flp, fl1_b, feat, Mpad);
    mgf(prot_x + 6165, 6485, wt_fl3, 320, fl3_b, feat, 480, 128, 320, 320, 320);

    // conv1: shared aggregation, fused pdb1+af1 GEMM -> hxy [Mpad][960]
    agg_wave_k<<<(N + 3) / 4, 256, 0, stream>>>(feat, tmp1, f_dinv, i_rowptr, i_csr, 60, 480, N);
    mg(tmp1, 480, wt_c1, 480, f_bias1, hxy, 960, 0, 480, 960, 960);
    // conv2: fused aggregation, two GEMMs -> zb [Mpad][1920]
    agg_block_k<<<N, 128, 0, stream>>>(hxy, tmp2, f_dinv, i_rowptr, i_csr, 120, 960, N);
    mg(tmp2,       960, wt_pdb2, 480, pdb2_b, zb, 1920, 0,   480, 938, 938);
    mg(tmp2 + 480, 960, wt_af2,  480, af2_b,  zb, 1920, 938, 480, 938, 982);
    // conv3
    agg_block_k<<<N, 256, 0, stream>>>(zb, zagg, f_dinv, i_rowptr, i_csr, 240, 1920, N);
    mg(zagg, 1920, wt_pdb3, 1920, pdb3_b, zout, 1888, 0, 1920, 1876, 1888);

    // pool + head
    pool_k<<<dim3(4, NG), 64, 0, stream>>>(zout, 1888, batch, f_pool, N, 1876);
    sgemm_part_k<<<dim3(16, 16), 256, 0, stream>>>(f_pool, 1876, fc1_W, 1024, f_part, 1876, 1024, 16);
    sgemm_reduce_k<<<(NG * 1024 + 255) / 256, 256, 0, stream>>>(f_part, fc1_b, f_fc1, 1024, 1024, 16, 0);
    bn_k<<<4, 256, 0, stream>>>(f_fc1, bn_g, bn_b, f_bn);
    sgemm_part_k<<<dim3(8, 16), 256, 0, stream>>>(f_bn, 1024, fc2_W, 486, f_part, 1024, 486, 16);
    sgemm_reduce_k<<<(NG * 486 + 255) / 256, 256, 0, stream>>>(f_part, fc2_b, (float*)d_out, 486, 486, 16, 2);
}

// Round 11
// 1568.577 us; speedup vs baseline: 1.2122x; 1.2122x over previous
//
#include <hip/hip_runtime.h>
#include <hip/hip_bf16.h>
#include <stdint.h>

#define NG 64

typedef __attribute__((ext_vector_type(8))) short bf16x8;
typedef __attribute__((ext_vector_type(4))) float f32x4;

#define AS1 __attribute__((address_space(1)))
#define AS3 __attribute__((address_space(3)))

static __device__ __forceinline__ unsigned short f2b(float f) {
    unsigned u = __float_as_uint(f);
    return (unsigned short)((u + 0x7fffu + ((u >> 16) & 1u)) >> 16);
}
static __device__ __forceinline__ float b2f(unsigned short h) {
    return __uint_as_float(((unsigned)h) << 16);
}
static __device__ __forceinline__ void gl16(const void* g, void* l) {
    __builtin_amdgcn_global_load_lds(
        (const AS1 void*)(uintptr_t)g,
        (AS3 void*)(unsigned)(uintptr_t)l, 16, 0, 0);
}
// bijective XCD-chunk swizzle (m204)
static __device__ __forceinline__ int xcd_swz(int bid, int nwg) {
    int q = nwg >> 3, r = nwg & 7;
    int xcd = bid & 7, oidx = bid >> 3;
    return (xcd < r ? xcd * (q + 1) : r * (q + 1) + (xcd - r) * q) + oidx;
}

// ---------------- graph build ----------------
__global__ void initcnt_k(int* cnt, int n) {
    int i = blockIdx.x * blockDim.x + threadIdx.x;
    if (i < n) cnt[i] = 0;
}
__global__ void count_k(const int* __restrict__ dst, int* cnt, int E) {
    int e = blockIdx.x * blockDim.x + threadIdx.x;
    if (e < E) atomicAdd(&cnt[dst[e]], 1);
}
__global__ void scan1_k(const int* __restrict__ cnt, int* __restrict__ scan,
                        int* __restrict__ bsum, int n) {
    __shared__ int wsum[16];
    int tid = threadIdx.x, lane = tid & 63, wid = tid >> 6;
    int i = blockIdx.x * 1024 + tid;
    int x = (i < n) ? cnt[i] : 0;
#pragma unroll
    for (int off = 1; off < 64; off <<= 1) {
        int t = __shfl_up(x, off);
        if (lane >= off) x += t;
    }
    if (lane == 63) wsum[wid] = x;
    __syncthreads();
    if (tid < 16) {
        int s = wsum[tid];
#pragma unroll
        for (int off = 1; off < 16; off <<= 1) {
            int t = __shfl_up(s, off);
            if (tid >= off) s += t;
        }
        wsum[tid] = s;
    }
    __syncthreads();
    int add = wid ? wsum[wid - 1] : 0;
    if (i < n) scan[i] = x + add;
    if (tid == 1023) bsum[blockIdx.x] = x + add;
}
__global__ void scan2_k(int* bsum, int nb) {
    int tid = threadIdx.x;
    int x = (tid < nb) ? bsum[tid] : 0;
#pragma unroll
    for (int off = 1; off < 64; off <<= 1) {
        int t = __shfl_up(x, off);
        if (tid >= off) x += t;
    }
    if (tid < nb) bsum[tid] = x;
}
__global__ void scan3f_k(const int* __restrict__ scan, const int* __restrict__ bsum,
                         const int* __restrict__ cnt,
                         int* __restrict__ rowptr, int* __restrict__ fill,
                         float* __restrict__ dinv, int n) {
    int i = blockIdx.x * blockDim.x + threadIdx.x;
    if (i >= n) return;
    int b = i >> 10;
    int rp1 = scan[i] + (b ? bsum[b - 1] : 0);
    rowptr[i + 1] = rp1;
    int rp0 = rp1 - cnt[i];
    if (i == 0) rowptr[0] = 0;
    fill[i] = rp0;
    dinv[i] = rsqrtf((float)(cnt[i] + 1));
}
__global__ void fill_k(const int* __restrict__ src, const int* __restrict__ dst,
                       int* fill, int* csr, int E) {
    int e = blockIdx.x * blockDim.x + threadIdx.x;
    if (e < E) {
        int d = dst[e];
        int pos = atomicAdd(&fill[d], 1);
        csr[pos] = src[e];
    }
}

// W [K][Nout] fp32 -> Wt rows [0,Nrows) x [0,Kpad) bf16 (transposed, zero-padded)
// remap=1: feat layout [f1(128)|f3(320)|f2(21)|pad]
__global__ void wtconv_k(const float* __restrict__ W, int K, int Nout,
                         unsigned short* __restrict__ Wt, int Kpad, int Nrows, int remap) {
    __shared__ float t[32][33];
    int k0 = blockIdx.x * 32, n0 = blockIdx.y * 32;
    int cx = threadIdx.x & 31, ry = threadIdx.x >> 5;
#pragma unroll
    for (int p = 0; p < 4; ++p) {
        int k = k0 + ry + p * 8, nn = n0 + cx;
        int ko = k;
        bool kvalid;
        if (remap) {
            ko = (k < 448) ? k + 21 : k - 448;
            kvalid = (k < 469);
        } else {
            kvalid = (k < K);
        }
        t[ry + p * 8][cx] = (kvalid && nn < Nout) ? W[(size_t)ko * Nout + nn] : 0.0f;
    }
    __syncthreads();
#pragma unroll
    for (int p = 0; p < 4; ++p) {
        int nn = n0 + ry + p * 8, k = k0 + cx;
        if (nn < Nrows) Wt[(size_t)nn * Kpad + k] = f2b(t[cx][ry + p * 8]);
    }
}

__global__ void biascat_k(const float* __restrict__ b0, const float* __restrict__ b1,
                          float* __restrict__ out) {
    int i = threadIdx.x + blockIdx.x * blockDim.x;
    if (i >= 960) return;
    int seg = i >= 480, c = i - seg * 480;
    const float* b = seg ? b1 : b0;
    out[i] = (c < 469) ? b[c] : 0.0f;
}

// ---------------- tiny fl2 (21x21) -> feat cols [448,480) ----------------
__global__ void fl2_k(const float* __restrict__ x, int ldx,
                      const float* __restrict__ W, const float* __restrict__ b,
                      unsigned short* __restrict__ out, int ldo, int n) {
    __shared__ float Ws[441];
    __shared__ float Bs[21];
    int tid = threadIdx.x;
    for (int i = tid; i < 441; i += 256) Ws[i] = W[i];
    if (tid < 21) Bs[tid] = b[tid];
    __syncthreads();
    int row = blockIdx.x * 256 + tid;
    if (row >= n) return;
    float xv[21];
#pragma unroll
    for (int j = 0; j < 21; ++j) xv[j] = x[(size_t)row * ldx + j];
    for (int c = 0; c < 32; ++c) {
        float v = 0.0f;
        if (c < 21) {
            float a = Bs[c];
#pragma unroll
            for (int j = 0; j < 21; ++j) a = fmaf(xv[j], Ws[j * 21 + c], a);
            v = fmaxf(a, 0.0f);
        }
        out[(size_t)row * ldo + 448 + c] = f2b(v);
    }
}

// ---------------- bf16 MFMA GEMM template: C = relu(A@W+b) ----------------
template<int NI, bool A32>
__global__ __launch_bounds__(256) void mgemm_t(
    const void* __restrict__ Aptr, int lda, int Mreal,
    const unsigned short* __restrict__ Bt, int ldb,
    const float* __restrict__ bias,
    unsigned short* __restrict__ C, int ldc, int coff,
    int K, int Nout, int Nzero, int GX) {
    constexpr int BNT = NI * 32;
    __shared__ unsigned short As[128 * 32];
    __shared__ unsigned short Bs[BNT * 32];
    const int tid = threadIdx.x;
    const int w = tid >> 6, lane = tid & 63;

    const int swz = xcd_swz(blockIdx.x, gridDim.x);
    const int m0 = (swz / GX) * 128, n0 = (swz % GX) * BNT;

    const int wr = w >> 1, wc = w & 1;

    f32x4 acc[4][NI];
#pragma unroll
    for (int i = 0; i < 4; ++i)
#pragma unroll
        for (int j = 0; j < NI; ++j) acc[i][j] = (f32x4){0.f, 0.f, 0.f, 0.f};

    const int ko = (lane >> 4) * 8;
    const int rA = wr * 64 + (lane & 15);
    const int rB = wc * (NI * 16) + (lane & 15);

    for (int k0 = 0; k0 < K; k0 += 32) {
        if constexpr (A32) {
            const float* Af = (const float*)Aptr;
#pragma unroll
            for (int j = 0; j < 2; ++j) {
                int c = w * 2 + j;
                int id2 = c * 64 + lane;
                int row = id2 >> 2, cc = id2 & 3;
                int gm = m0 + row; if (gm > Mreal - 1) gm = Mreal - 1;
                const float* ap = Af + (size_t)gm * lda + k0 + cc * 8;
                float4 v0 = *(const float4*)ap;
                float4 v1 = *(const float4*)(ap + 4);
                unsigned short t[8] = {f2b(v0.x), f2b(v0.y), f2b(v0.z), f2b(v0.w),
                                       f2b(v1.x), f2b(v1.y), f2b(v1.z), f2b(v1.w)};
                *(bf16x8*)&As[row * 32 + cc * 8] = *(const bf16x8*)t;
            }
        } else {
            const unsigned short* Ab = (const unsigned short*)Aptr;
#pragma unroll
            for (int j = 0; j < 2; ++j) {
                int c = w * 2 + j;
                int id2 = c * 64 + lane;
                int row = id2 >> 2, cc = id2 & 3;
                gl16(Ab + (size_t)(m0 + row) * lda + k0 + cc * 8, &As[c * 512]);
            }
        }
#pragma unroll
        for (int j = 0; j < NI / 2; ++j) {
            int c = w * (NI / 2) + j;
            int id2 = c * 64 + lane;
            int row = id2 >> 2, cc = id2 & 3;
            gl16(Bt + (size_t)(n0 + row) * ldb + k0 + cc * 8, &Bs[c * 512]);
        }
        __syncthreads();
        bf16x8 a[4], b[NI];
#pragma unroll
        for (int i = 0; i < 4; ++i) a[i] = *(const bf16x8*)&As[(rA + i * 16) * 32 + ko];
#pragma unroll
        for (int j = 0; j < NI; ++j) b[j] = *(const bf16x8*)&Bs[(rB + j * 16) * 32 + ko];
#pragma unroll
        for (int i = 0; i < 4; ++i)
#pragma unroll
            for (int j = 0; j < NI; ++j)
                acc[i][j] = __builtin_amdgcn_mfma_f32_16x16x32_bf16(a[i], b[j], acc[i][j], 0, 0, 0);
        __syncthreads();
    }

    const int cn = lane & 15, r4 = (lane >> 4) * 4;
    for (int ni = 0; ni < NI; ++ni) {
        int col = n0 + wc * (NI * 16) + ni * 16 + cn;
        if (col >= Nzero) continue;
        bool real = col < Nout;
        float bb = real ? bias[col] : 0.0f;
#pragma unroll
        for (int mi = 0; mi < 4; ++mi) {
#pragma unroll
            for (int rr = 0; rr < 4; ++rr) {
                int row = m0 + wr * 64 + mi * 16 + r4 + rr;
                float x = real ? fmaxf(acc[mi][ni][rr] + bb, 0.0f) : 0.0f;
                C[(size_t)row * ldc + coff + col] = f2b(x);
            }
        }
    }
}

// ---------------- fl1 split-K (ksplit=3, K-chunk 2048) ----------------
__global__ __launch_bounds__(256) void fl1part_k(
    const float* __restrict__ A, int lda, int Mreal,
    const unsigned short* __restrict__ Bt, int ldb,
    float* __restrict__ part, int MT, int Mpad) {
    __shared__ unsigned short As[128 * 32];
    __shared__ unsigned short Bs[128 * 32];
    const int tid = threadIdx.x;
    const int w = tid >> 6, lane = tid & 63;
    const int mt = blockIdx.x % MT, ks = blockIdx.x / MT;
    const int m0 = mt * 128;
    const int kbeg = ks * 2048, kend = kbeg + 2048;
    const int wr = w >> 1, wc = w & 1;

    f32x4 acc[4][4];
#pragma unroll
    for (int i = 0; i < 4; ++i)
#pragma unroll
        for (int j = 0; j < 4; ++j) acc[i][j] = (f32x4){0.f, 0.f, 0.f, 0.f};

    const int ko = (lane >> 4) * 8;
    const int rA = wr * 64 + (lane & 15);
    const int rB = wc * 64 + (lane & 15);

    for (int k0 = kbeg; k0 < kend; k0 += 32) {
#pragma unroll
        for (int j = 0; j < 2; ++j) {
            int c = w * 2 + j;
            int id2 = c * 64 + lane;
            int row = id2 >> 2, cc = id2 & 3;
            int gm = m0 + row; if (gm > Mreal - 1) gm = Mreal - 1;
            const float* ap = A + (size_t)gm * lda + k0 + cc * 8;
            float4 v0 = *(const float4*)ap;
            float4 v1 = *(const float4*)(ap + 4);
            unsigned short t[8] = {f2b(v0.x), f2b(v0.y), f2b(v0.z), f2b(v0.w),
                                   f2b(v1.x), f2b(v1.y), f2b(v1.z), f2b(v1.w)};
            *(bf16x8*)&As[row * 32 + cc * 8] = *(const bf16x8*)t;
            gl16(Bt + (size_t)row * ldb + k0 + cc * 8, &Bs[c * 512]);
        }
        __syncthreads();
        bf16x8 a[4], b[4];
#pragma unroll
        for (int i = 0; i < 4; ++i) a[i] = *(const bf16x8*)&As[(rA + i * 16) * 32 + ko];
#pragma unroll
        for (int j = 0; j < 4; ++j) b[j] = *(const bf16x8*)&Bs[(rB + j * 16) * 32 + ko];
#pragma unroll
        for (int i = 0; i < 4; ++i)
#pragma unroll
            for (int j = 0; j < 4; ++j)
                acc[i][j] = __builtin_amdgcn_mfma_f32_16x16x32_bf16(a[i], b[j], acc[i][j], 0, 0, 0);
        __syncthreads();
    }

    float* pb = part + (size_t)ks * Mpad * 128;
    const int cn = lane & 15, r4 = (lane >> 4) * 4;
#pragma unroll
    for (int ni = 0; ni < 4; ++ni) {
        int col = wc * 64 + ni * 16 + cn;
#pragma unroll
        for (int mi = 0; mi < 4; ++mi) {
#pragma unroll
            for (int rr = 0; rr < 4; ++rr) {
                int row = m0 + wr * 64 + mi * 16 + r4 + rr;
                pb[(size_t)row * 128 + col] = acc[mi][ni][rr];
            }
        }
    }
}

__global__ void fl1red_k(const float* __restrict__ part, const float* __restrict__ bias,
                         unsigned short* __restrict__ feat, int Mpad) {
    int i = blockIdx.x * blockDim.x + threadIdx.x;
    if (i >= Mpad * 32) return;
    int row = i >> 5, c = (i & 31) * 4;
    size_t base = (size_t)row * 128 + c;
    size_t stride = (size_t)Mpad * 128;
    float4 p0 = *(const float4*)(part + base);
    float4 p1 = *(const float4*)(part + stride + base);
    float4 p2 = *(const float4*)(part + 2 * stride + base);
    float4 bb = *(const float4*)(bias + c);
    ushort4 o;
    o.x = f2b(fmaxf(p0.x + p1.x + p2.x + bb.x, 0.0f));
    o.y = f2b(fmaxf(p0.y + p1.y + p2.y + bb.y, 0.0f));
    o.z = f2b(fmaxf(p0.z + p1.z + p2.z + bb.z, 0.0f));
    o.w = f2b(fmaxf(p0.w + p1.w + p2.w + bb.w, 0.0f));
    *(ushort4*)(feat + (size_t)row * 480 + c) = o;
}

// ---------------- GCN aggregation (XCD-chunked node assignment) ----------------
__global__ __launch_bounds__(256) void agg_wave_k(
    const unsigned short* __restrict__ in, unsigned short* __restrict__ out,
    const float* __restrict__ dinv, const int* __restrict__ rowptr,
    const int* __restrict__ csr, int D8, int ld, int n) {
    int lane = threadIdx.x & 63;
    int node = xcd_swz(blockIdx.x, gridDim.x) * 4 + (threadIdx.x >> 6);
    if (node >= n) return;
    bool act = lane < D8;
    float di = dinv[node];
    float acc[8];
#pragma unroll
    for (int t = 0; t < 8; ++t) acc[t] = 0.0f;
    if (act) {
        bf16x8 v = *(const bf16x8*)(in + (size_t)node * ld + lane * 8);
#pragma unroll
        for (int t = 0; t < 8; ++t) acc[t] = di * b2f((unsigned short)v[t]);
    }
    int s = rowptr[node], e = rowptr[node + 1];
    for (int c = s; c < e; c += 64) {
        int m = e - c; if (m > 64) m = 64;
        int idx = (c + lane < e) ? csr[c + lane] : 0;
        float wl = dinv[idx];
        for (int j = 0; j < m; ++j) {
            int src = __shfl(idx, j);
            float wgt = __shfl(wl, j);
            if (act) {
                bf16x8 v = *(const bf16x8*)(in + (size_t)src * ld + lane * 8);
#pragma unroll
                for (int t = 0; t < 8; ++t) acc[t] = fmaf(wgt, b2f((unsigned short)v[t]), acc[t]);
            }
        }
    }
    if (act) {
        unsigned short o[8];
#pragma unroll
        for (int t = 0; t < 8; ++t) o[t] = f2b(di * acc[t]);
        *(bf16x8*)(out + (size_t)node * ld + lane * 8) = *(const bf16x8*)o;
    }
}

__global__ void agg_block_k(
    const unsigned short* __restrict__ in, unsigned short* __restrict__ out,
    const float* __restrict__ dinv, const int* __restrict__ rowptr,
    const int* __restrict__ csr, int D8, int ld, int n) {
    int i = xcd_swz(blockIdx.x, gridDim.x);
    int tid = threadIdx.x;
    __shared__ int s_src[64];
    __shared__ float s_w[64];
    bool act = tid < D8;
    float di = dinv[i];
    float acc[8];
#pragma unroll
    for (int t = 0; t < 8; ++t) acc[t] = 0.0f;
    if (act) {
        bf16x8 v = *(const bf16x8*)(in + (size_t)i * ld + tid * 8);
#pragma unroll
        for (int t = 0; t < 8; ++t) acc[t] = di * b2f((unsigned short)v[t]);
    }
    int s = rowptr[i], e = rowptr[i + 1];
    for (int c = s; c < e; c += 64) {
        int k = c + tid;
        if (tid < 64 && k < e) { int sn = csr[k]; s_src[tid] = sn; s_w[tid] = dinv[sn]; }
        __syncthreads();
        int m = e - c; if (m > 64) m = 64;
        for (int j = 0; j < m; ++j) {
            int sn = s_src[j];
            float wgt = s_w[j];
            if (act) {
                bf16x8 v = *(const bf16x8*)(in + (size_t)sn * ld + tid * 8);
#pragma unroll
                for (int t = 0; t < 8; ++t) acc[t] = fmaf(wgt, b2f((unsigned short)v[t]), acc[t]);
            }
        }
        __syncthreads();
    }
    if (act) {
        unsigned short o[8];
#pragma unroll
        for (int t = 0; t < 8; ++t) o[t] = f2b(di * acc[t]);
        *(bf16x8*)(out + (size_t)i * ld + tid * 8) = *(const bf16x8*)o;
    }
}

// ---------------- mean pool (vectorized bf16x8) ----------------
__global__ void pool_k(const unsigned short* __restrict__ in, int ld,
                       const int* __restrict__ batch,
                       float* __restrict__ out, int n, int D) {
    int g = blockIdx.y;
    int d8 = blockIdx.x * blockDim.x + threadIdx.x;
    if (d8 * 8 >= ld) return;
    int lo = 0, hi = n;
    while (lo < hi) { int mid = (lo + hi) >> 1; if (batch[mid] < g) lo = mid + 1; else hi = mid; }
    int start = lo;
    lo = start; hi = n;
    while (lo < hi) { int mid = (lo + hi) >> 1; if (batch[mid] < g + 1) lo = mid + 1; else hi = mid; }
    int end = lo;
    float s[8];
#pragma unroll
    for (int j = 0; j < 8; ++j) s[j] = 0.0f;
#pragma unroll 4
    for (int r = start; r < end; r++) {
        bf16x8 v = *(const bf16x8*)(in + (size_t)r * ld + d8 * 8);
#pragma unroll
        for (int j = 0; j < 8; ++j) s[j] += b2f((unsigned short)v[j]);
    }
    float inv = 1.0f / fmaxf((float)(end - start), 1.0f);
#pragma unroll
    for (int j = 0; j < 8; ++j) {
        int d = d8 * 8 + j;
        if (d < D) out[(size_t)g * D + d] = s[j] * inv;
    }
}

// ---------------- skinny head GEMM ----------------
__global__ __launch_bounds__(256) void sgemm_part_k(
    const float* __restrict__ A, int lda,
    const float* __restrict__ W, int ldw,
    float* __restrict__ part, int K, int Nout, int ksplit) {
    const int n0 = blockIdx.x * 64;
    const int ks = blockIdx.y;
    const int kbeg = (int)(((long long)K * ks) / ksplit);
    const int kend = (int)(((long long)K * (ks + 1)) / ksplit);
    const int tx = threadIdx.x & 63, ty = threadIdx.x >> 6;
    __shared__ float As[64][65];
    float acc[16];
#pragma unroll
    for (int r = 0; r < 16; ++r) acc[r] = 0.0f;

    for (int kb = kbeg; kb < kend; kb += 64) {
        int kc = kend - kb; if (kc > 64) kc = 64;
        for (int i = threadIdx.x; i < 64 * 64; i += 256) {
            int r = i >> 6, c = i & 63;
            As[r][c] = (c < kc) ? A[(size_t)r * lda + kb + c] : 0.0f;
        }
        __syncthreads();
        if (n0 + tx < Nout) {
            for (int k = 0; k < kc; ++k) {
                float w = W[(size_t)(kb + k) * ldw + n0 + tx];
#pragma unroll
                for (int r = 0; r < 16; ++r)
                    acc[r] = fmaf(As[ty * 16 + r][k], w, acc[r]);
            }
        }
        __syncthreads();
    }
    if (n0 + tx < Nout) {
#pragma unroll
        for (int r = 0; r < 16; ++r)
            part[((size_t)ks * 64 + ty * 16 + r) * Nout + n0 + tx] = acc[r];
    }
}

__global__ void sgemm_reduce_k(const float* __restrict__ part, const float* __restrict__ bias,
                               float* __restrict__ C, int ldc, int Nout, int ksplit, int act) {
    int i = blockIdx.x * blockDim.x + threadIdx.x;
    if (i >= NG * Nout) return;
    int m = i / Nout, n = i - m * Nout;
    float v = bias[n];
    for (int s = 0; s < ksplit; ++s) v += part[((size_t)s * 64 + m) * Nout + n];
    if (act == 2) v = 1.0f / (1.0f + expf(-v));
    C[(size_t)m * ldc + n] = v;
}

// ---------------- fused batchnorm ----------------
__global__ void bn_k(const float* __restrict__ z, const float* __restrict__ g,
                     const float* __restrict__ b, float* __restrict__ out) {
    int c = blockIdx.x * blockDim.x + threadIdx.x;
    if (c >= 1024) return;
    float s = 0.0f, s2 = 0.0f;
    for (int r = 0; r < NG; r++) { float v = z[r * 1024 + c]; s += v; s2 += v * v; }
    float mu = s / (float)NG;
    float var = s2 / (float)NG - mu * mu;
    float sc = g[c] * rsqrtf(var + 1e-5f);
    float sh = b[c] - mu * sc;
    for (int r = 0; r < NG; r++)
        out[r * 1024 + c] = fmaxf(fmaf(z[r * 1024 + c], sc, sh), 0.0f);
}

// ---------------- launch ----------------
extern "C" void kernel_launch(void* const* d_in, const int* in_sizes, int n_in,
                              void* d_out, int out_size, void* d_ws, size_t ws_size,
                              hipStream_t stream) {
    (void)n_in; (void)out_size; (void)ws_size;
    const float* prot_x = (const float*)d_in[0];
    const int*   eidx   = (const int*)d_in[1];
    const int*   batch  = (const int*)d_in[2];
    const float* fl1_W = (const float*)d_in[3],  *fl1_b = (const float*)d_in[4];
    const float* fl2_W = (const float*)d_in[5],  *fl2_b = (const float*)d_in[6];
    const float* fl3_W = (const float*)d_in[7],  *fl3_b = (const float*)d_in[8];
    const float* pdb1_W = (const float*)d_in[9],  *pdb1_b = (const float*)d_in[10];
    const float* pdb2_W = (const float*)d_in[11], *pdb2_b = (const float*)d_in[12];
    const float* af1_W  = (const float*)d_in[13], *af1_b  = (const float*)d_in[14];
    const float* af2_W  = (const float*)d_in[15], *af2_b  = (const float*)d_in[16];
    const float* pdb3_W = (const float*)d_in[17], *pdb3_b = (const float*)d_in[18];
    const float* fc1_W  = (const float*)d_in[19], *fc1_b  = (const float*)d_in[20];
    const float* bn_g   = (const float*)d_in[21], *bn_b   = (const float*)d_in[22];
    const float* fc2_W  = (const float*)d_in[23], *fc2_b  = (const float*)d_in[24];

    const int N = in_sizes[2];
    const int E = in_sizes[1] / 2;
    const int* e_src = eidx;
    const int* e_dst = eidx + E;
    const int Mpad = ((N + 127) / 128) * 128;
    const int MT = Mpad / 128;
    const int NB = (N + 1023) / 1024;

    // ---------- workspace ----------
    char* wp = (char*)d_ws;
    auto alloc = [&](size_t bytes) -> char* {
        char* r = wp; wp += (bytes + 255) & ~(size_t)255; return r;
    };
    unsigned short* feat = (unsigned short*)alloc((size_t)Mpad * 480 * 2);
    unsigned short* tmp1 = (unsigned short*)alloc((size_t)Mpad * 480 * 2);
    unsigned short* hxy  = (unsigned short*)alloc((size_t)Mpad * 960 * 2);
    unsigned short* tmp2 = (unsigned short*)alloc((size_t)Mpad * 960 * 2);
    unsigned short* zb   = (unsigned short*)alloc((size_t)Mpad * 1920 * 2);
    unsigned short* zagg = (unsigned short*)alloc((size_t)Mpad * 1920 * 2);
    unsigned short* zout = (unsigned short*)alloc((size_t)Mpad * 1888 * 2);
    unsigned short* wt_fl1  = (unsigned short*)alloc((size_t)128 * 6144 * 2);
    unsigned short* wt_fl3  = (unsigned short*)alloc((size_t)384 * 320 * 2);
    unsigned short* wt_c1   = (unsigned short*)alloc((size_t)1024 * 480 * 2);
    unsigned short* wt_pdb2 = (unsigned short*)alloc((size_t)1024 * 480 * 2);
    unsigned short* wt_af2  = (unsigned short*)alloc((size_t)1152 * 480 * 2);
    unsigned short* wt_pdb3 = (unsigned short*)alloc((size_t)1920 * 1920 * 2);
    float* f_bias1 = (float*)alloc(960 * 4);
    float* f_dinv = (float*)alloc((size_t)N * 4);
    float* f_pool = (float*)alloc((size_t)NG * 1876 * 4);
    float* f_fc1  = (float*)alloc((size_t)NG * 1024 * 4);
    float* f_bn   = (float*)alloc((size_t)NG * 1024 * 4);
    float* f_part = (float*)alloc((size_t)16 * 64 * 1024 * 4);
    float* f_flp  = (float*)alloc((size_t)3 * Mpad * 128 * 4);
    int* i_cnt    = (int*)alloc((size_t)N * 4);
    int* i_scan   = (int*)alloc((size_t)N * 4);
    int* i_bsum   = (int*)alloc(64 * 4);
    int* i_rowptr = (int*)alloc((size_t)(N + 1) * 4);
    int* i_fill   = (int*)alloc((size_t)N * 4);
    int* i_csr    = (int*)alloc((size_t)E * 4);

    // NI=6 (BN=192) bf16-A GEMM
    auto mg = [&](const unsigned short* A, int lda, const unsigned short* Wt, int ldb,
                  const float* bias, unsigned short* C, int ldc, int coff,
                  int K, int Nout, int Nzero) {
        int gx = (Nzero + 191) / 192;
        mgemm_t<6, false><<<gx * MT, 256, 0, stream>>>(
            A, lda, Mpad, Wt, ldb, bias, C, ldc, coff, K, Nout, Nzero, gx);
    };
    // NI=4 (BN=128) fp32-A GEMM
    auto mgf = [&](const float* A, int lda, const unsigned short* Wt, int ldb,
                   const float* bias, unsigned short* C, int ldc, int coff,
                   int K, int Nout, int Nzero) {
        int gx = (Nzero + 127) / 128;
        mgemm_t<4, true><<<gx * MT, 256, 0, stream>>>(
            A, lda, N, Wt, ldb, bias, C, ldc, coff, K, Nout, Nzero, gx);
    };
    auto wt = [&](const float* W, int K, int Nout, unsigned short* Wt, int Kpad, int Nrows, int remap) {
        wtconv_k<<<dim3(Kpad / 32, Nrows / 32), 256, 0, stream>>>(W, K, Nout, Wt, Kpad, Nrows, remap);
    };

    // graph build
    initcnt_k<<<(N + 255) / 256, 256, 0, stream>>>(i_cnt, N);
    count_k<<<(E + 255) / 256, 256, 0, stream>>>(e_dst, i_cnt, E);
    scan1_k<<<NB, 1024, 0, stream>>>(i_cnt, i_scan, i_bsum, N);
    scan2_k<<<1, 64, 0, stream>>>(i_bsum, NB);
    scan3f_k<<<(N + 255) / 256, 256, 0, stream>>>(i_scan, i_bsum, i_cnt, i_rowptr, i_fill, f_dinv, N);
    fill_k<<<(E + 255) / 256, 256, 0, stream>>>(e_src, e_dst, i_fill, i_csr, E);

    // weight prep (feat layout: [f1(128) | f3(320) | f2(21) | pad(11)])
    wt(fl1_W, 6144, 128, wt_fl1, 6144, 128, 0);
    wt(fl3_W, 320, 320, wt_fl3, 320, 384, 0);
    wt(pdb1_W, 469, 469, wt_c1, 480, 480, 1);
    wt(af1_W, 469, 469, wt_c1 + (size_t)480 * 480, 480, 544, 1);
    wt(pdb2_W, 469, 938, wt_pdb2, 480, 1024, 0);
    wt(af2_W, 469, 938, wt_af2, 480, 1152, 0);
    wt(pdb3_W, 1876, 1876, wt_pdb3, 1920, 1920, 0);
    biascat_k<<<4, 256, 0, stream>>>(pdb1_b, af1_b, f_bias1);

    // feature linears
    fl2_k<<<(N + 255) / 256, 256, 0, stream>>>(prot_x, 6485, fl2_W, fl2_b, feat, 480, N);
    fl1part_k<<<MT * 3, 256, 0, stream>>>(prot_x + 21, 6485, N, wt_fl1, 6144, f_flp, MT, Mpad);
    fl1red_k<<<(Mpad * 32 + 255) / 256, 256, 0, stream>>>(f_flp, fl1_b, feat, Mpad);
    mgf(prot_x + 6165, 6485, wt_fl3, 320, fl3_b, feat, 480, 128, 320, 320, 320);

    // conv1: shared aggregation, fused pdb1+af1 GEMM -> hxy [Mpad][960]
    agg_wave_k<<<(N + 3) / 4, 256, 0, stream>>>(feat, tmp1, f_dinv, i_rowptr, i_csr, 60, 480, N);
    mg(tmp1, 480, wt_c1, 480, f_bias1, hxy, 960, 0, 480, 960, 960);
    // conv2: fused aggregation, two GEMMs -> zb [Mpad][1920]
    agg_block_k<<<N, 128, 0, stream>>>(hxy, tmp2, f_dinv, i_rowptr, i_csr, 120, 960, N);
    mg(tmp2,       960, wt_pdb2, 480, pdb2_b, zb, 1920, 0,   480, 938, 938);
    mg(tmp2 + 480, 960, wt_af2,  480, af2_b,  zb, 1920, 938, 480, 938, 982);
    // conv3
    agg_block_k<<<N, 256, 0, stream>>>(zb, zagg, f_dinv, i_rowptr, i_csr, 240, 1920, N);
    mg(zagg, 1920, wt_pdb3, 1920, pdb3_b, zout, 1888, 0, 1920, 1876, 1888);

    // pool + head
    pool_k<<<dim3(4, NG), 64, 0, stream>>>(zout, 1888, batch, f_pool, N, 1876);
    sgemm_part_k<<<dim3(16, 16), 256, 0, stream>>>(f_pool, 1876, fc1_W, 1024, f_part, 1876, 1024, 16);
    sgemm_reduce_k<<<(NG * 1024 + 255) / 256, 256, 0, stream>>>(f_part, fc1_b, f_fc1, 1024, 1024, 16, 0);
    bn_k<<<4, 256, 0, stream>>>(f_fc1, bn_g, bn_b, f_bn);
    sgemm_part_k<<<dim3(8, 16), 256, 0, stream>>>(f_bn, 1024, fc2_W, 486, f_part, 1024, 486, 16);
    sgemm_reduce_k<<<(NG * 486 + 255) / 256, 256, 0, stream>>>(f_part, fc2_b, (float*)d_out, 486, 486, 16, 2);
}